// Round 13
// baseline (10691.765 us; speedup 1.0000x reference)
//
#include <hip/hip_runtime.h>

// ChebConv GNN: 6 layers x (K=5 Chebyshev), 50000 nodes / 640000 edges, WIDTH=128.
//  - CSR (packed int2 {src,norm}) built once per launch; hierarchical scan (dinv fused).
//  - ONE mega-kernel (plain launch, 1024 blocks) runs all 6 layers with a hand-rolled
//    generation grid-barrier (device-scope atomics). Co-residency guaranteed:
//    __launch_bounds__(256,4) caps VGPR=128; LDS 27.6KB*4=110KB<160KB -> 4 blocks/CU.
//    Spin has a bounded timeout: a co-residency miss degrades to wrong answer, not hang.
//  - prop: 16 lanes/node, uint4 gathers, shfl-broadcast descriptors, 4-deep unroll
//    (R11 A/B: 8-deep regresses). fp32 accumulate, bf16 store.
//  - GEMM: LDS-staged 64x128 tile, BK=64, register prefetch; final layer fuses
//    Linear(128->1) via shfl_xor reduce.
//  NOTE (R9): __builtin_nontemporal_* scalarizes vector accesses on gfx950 - avoid.
//  NOTE (R12): hipLaunchCooperativeKernel silently no-ops in this harness - avoid.

#define NN 50000
#define NE 640000
#define WID 128
#define GBLK 1024

typedef __attribute__((ext_vector_type(8))) short bf16x8;
typedef __attribute__((ext_vector_type(4))) float f32x4;

__device__ __forceinline__ unsigned short f2bf(float f) {
  union { float f; unsigned int u; } v; v.f = f;
  unsigned int r = v.u + 0x7FFF + ((v.u >> 16) & 1);  // RNE
  return (unsigned short)(r >> 16);
}
__device__ __forceinline__ unsigned int pack2(float lo, float hi) {
  return (unsigned int)f2bf(lo) | ((unsigned int)f2bf(hi) << 16);
}
__device__ __forceinline__ float bflo(unsigned int u) {
  return __uint_as_float(u << 16);
}
__device__ __forceinline__ float bfhi(unsigned int u) {
  return __uint_as_float(u & 0xffff0000u);
}

// ---------------- preprocessing ----------------

__global__ __launch_bounds__(256) void degree_kernel(const int* __restrict__ ei,
                                                     int* __restrict__ deg, int E) {
  int e = blockIdx.x * 256 + threadIdx.x;
  if (e < E) atomicAdd(&deg[ei[E + e]], 1);
}

__global__ __launch_bounds__(256) void scan1_kernel(const int* __restrict__ deg,
                                                    int* __restrict__ lex,
                                                    int* __restrict__ bsum,
                                                    float* __restrict__ dinv, int n) {
  __shared__ int ws[4];
  int tid = threadIdx.x, lane = tid & 63, w = tid >> 6;
  int i = blockIdx.x * 256 + tid;
  int cnt = (i < n) ? deg[i] : 0;
  if (i < n) {
    float d = (float)cnt;
    dinv[i] = d > 0.0f ? rsqrtf(d) : 0.0f;
  }
  int v = cnt;
#pragma unroll
  for (int off = 1; off < 64; off <<= 1) {
    int u = __shfl_up(v, off, 64);
    if (lane >= off) v += u;
  }
  if (lane == 63) ws[w] = v;
  __syncthreads();
  int wexcl = 0;
#pragma unroll
  for (int k = 0; k < 4; ++k) wexcl += (k < w) ? ws[k] : 0;
  if (i < n) lex[i] = wexcl + v - cnt;
  if (tid == 255) bsum[blockIdx.x] = wexcl + v;
}

__global__ __launch_bounds__(256) void scan2_kernel(const int* __restrict__ bsum,
                                                    int* __restrict__ boff,
                                                    int* __restrict__ row_end, int nb) {
  __shared__ int ws[4];
  int tid = threadIdx.x, lane = tid & 63, w = tid >> 6;
  int cnt = (tid < nb) ? bsum[tid] : 0;
  int v = cnt;
#pragma unroll
  for (int off = 1; off < 64; off <<= 1) {
    int u = __shfl_up(v, off, 64);
    if (lane >= off) v += u;
  }
  if (lane == 63) ws[w] = v;
  __syncthreads();
  int wexcl = 0;
#pragma unroll
  for (int k = 0; k < 4; ++k) wexcl += (k < w) ? ws[k] : 0;
  if (tid < nb) boff[tid] = wexcl + v - cnt;
  if (tid == 255) *row_end = wexcl + v;
}

__global__ __launch_bounds__(256) void scan3_kernel(const int* __restrict__ lex,
                                                    const int* __restrict__ boff,
                                                    int* __restrict__ row_start,
                                                    int* __restrict__ fill_ptr, int n) {
  int i = blockIdx.x * 256 + threadIdx.x;
  if (i < n) {
    int rs = lex[i] + boff[blockIdx.x];
    row_start[i] = rs;
    fill_ptr[i] = rs;
  }
}

__global__ __launch_bounds__(256) void fill_kernel(const int* __restrict__ ei,
                                                   const float* __restrict__ dinv,
                                                   int* __restrict__ fill_ptr,
                                                   int2* __restrict__ csr, int E) {
  int e = blockIdx.x * 256 + threadIdx.x;
  if (e < E) {
    int s = ei[e];
    int d = ei[E + e];
    int pos = atomicAdd(&fill_ptr[d], 1);
    csr[pos] = make_int2(s, __float_as_int(-dinv[s] * dinv[d]));
  }
}

__global__ __launch_bounds__(256) void cvt_x_kernel(const float* __restrict__ x,
                                                    unsigned short* __restrict__ o, int n) {
  int i = blockIdx.x * 256 + threadIdx.x;
  if (i < n) o[i] = f2bf(x[i]);
}

// conv_w [6][5][128][128] fp32 -> Wt [6][128 cols][640 k] bf16   (k = kk*128 + m)
__global__ __launch_bounds__(256) void cvt_w_kernel(const float* __restrict__ w,
                                                    unsigned short* __restrict__ wt, int n) {
  int i = blockIdx.x * 256 + threadIdx.x;
  if (i < n) {
    int l = i / (WID * 640);
    int r = i % (WID * 640);
    int col = r / 640;
    int k = r % 640;
    int kk = k >> 7, m = k & 127;
    wt[i] = f2bf(w[(((size_t)l * 5 + kk) * WID + m) * WID + col]);
  }
}

// ---------------- grid barrier (generation counting, device-scope atomics) ----------------

__device__ __forceinline__ void gsync(int* __restrict__ cnt, int* __restrict__ gen_done,
                                      int& gen) {
  __threadfence();       // release: push this block's writes toward coherence point
  __syncthreads();
  if (threadIdx.x == 0) {
    ++gen;
    int prev = __hip_atomic_fetch_add(cnt, 1, __ATOMIC_ACQ_REL, __HIP_MEMORY_SCOPE_AGENT);
    if (prev == gen * GBLK - 1) {
      __hip_atomic_store(gen_done, gen, __ATOMIC_RELEASE, __HIP_MEMORY_SCOPE_AGENT);
    } else {
      long long tries = 0;
      while (__hip_atomic_load(gen_done, __ATOMIC_ACQUIRE, __HIP_MEMORY_SCOPE_AGENT) < gen) {
        __builtin_amdgcn_s_sleep(8);
        if (++tries > (long long)50000000) break;  // safety: degrade, never hang
      }
    }
  } else {
    ++gen;
  }
  __syncthreads();
  __threadfence();       // acquire: invalidate stale cached lines for every wave
}

// ---------------- device phases ----------------

__device__ __forceinline__ void prop_phase(unsigned short* __restrict__ out,
                                           const unsigned short* __restrict__ xin,
                                           const unsigned short* __restrict__ sub,
                                           float scale,
                                           const int* __restrict__ row_start,
                                           const int2* __restrict__ csr, int n) {
  int t = threadIdx.x & 15;
  for (int node = blockIdx.x * 16 + (threadIdx.x >> 4); node < n;
       node += GBLK * 16) {
    int s = row_start[node], e = row_start[node + 1];
    float a0 = 0.f, a1 = 0.f, a2 = 0.f, a3 = 0.f;
    float a4 = 0.f, a5 = 0.f, a6 = 0.f, a7 = 0.f;
    for (int base = s; base < e; base += 16) {
      int cnt = min(16, e - base);
      int2 ed = (t < cnt) ? csr[base + t] : make_int2(0, 0);
      int j = 0;
      for (; j + 4 <= cnt; j += 4) {
        int s0 = __shfl(ed.x, j, 16), s1 = __shfl(ed.x, j + 1, 16);
        int s2 = __shfl(ed.x, j + 2, 16), s3 = __shfl(ed.x, j + 3, 16);
        float n0 = __int_as_float(__shfl(ed.y, j, 16));
        float n1 = __int_as_float(__shfl(ed.y, j + 1, 16));
        float n2 = __int_as_float(__shfl(ed.y, j + 2, 16));
        float n3 = __int_as_float(__shfl(ed.y, j + 3, 16));
        const uint4 v0 = *(const uint4*)(xin + (size_t)s0 * WID + t * 8);
        const uint4 v1 = *(const uint4*)(xin + (size_t)s1 * WID + t * 8);
        const uint4 v2 = *(const uint4*)(xin + (size_t)s2 * WID + t * 8);
        const uint4 v3 = *(const uint4*)(xin + (size_t)s3 * WID + t * 8);
        a0 += n0 * bflo(v0.x) + n1 * bflo(v1.x) + n2 * bflo(v2.x) + n3 * bflo(v3.x);
        a1 += n0 * bfhi(v0.x) + n1 * bfhi(v1.x) + n2 * bfhi(v2.x) + n3 * bfhi(v3.x);
        a2 += n0 * bflo(v0.y) + n1 * bflo(v1.y) + n2 * bflo(v2.y) + n3 * bflo(v3.y);
        a3 += n0 * bfhi(v0.y) + n1 * bfhi(v1.y) + n2 * bfhi(v2.y) + n3 * bfhi(v3.y);
        a4 += n0 * bflo(v0.z) + n1 * bflo(v1.z) + n2 * bflo(v2.z) + n3 * bflo(v3.z);
        a5 += n0 * bfhi(v0.z) + n1 * bfhi(v1.z) + n2 * bfhi(v2.z) + n3 * bfhi(v3.z);
        a6 += n0 * bflo(v0.w) + n1 * bflo(v1.w) + n2 * bflo(v2.w) + n3 * bflo(v3.w);
        a7 += n0 * bfhi(v0.w) + n1 * bfhi(v1.w) + n2 * bfhi(v2.w) + n3 * bfhi(v3.w);
      }
      for (; j < cnt; ++j) {
        int sj = __shfl(ed.x, j, 16);
        float nj = __int_as_float(__shfl(ed.y, j, 16));
        const uint4 v = *(const uint4*)(xin + (size_t)sj * WID + t * 8);
        a0 += nj * bflo(v.x); a1 += nj * bfhi(v.x);
        a2 += nj * bflo(v.y); a3 += nj * bfhi(v.y);
        a4 += nj * bflo(v.z); a5 += nj * bfhi(v.z);
        a6 += nj * bflo(v.w); a7 += nj * bfhi(v.w);
      }
    }
    size_t o = (size_t)node * WID + t * 8;
    float r0 = scale * a0, r1 = scale * a1, r2 = scale * a2, r3 = scale * a3;
    float r4 = scale * a4, r5 = scale * a5, r6 = scale * a6, r7 = scale * a7;
    if (sub) {
      const uint4 sv = *(const uint4*)(sub + o);
      r0 -= bflo(sv.x); r1 -= bfhi(sv.x);
      r2 -= bflo(sv.y); r3 -= bfhi(sv.y);
      r4 -= bflo(sv.z); r5 -= bfhi(sv.z);
      r6 -= bflo(sv.w); r7 -= bfhi(sv.w);
    }
    uint4 wv;
    wv.x = pack2(r0, r1); wv.y = pack2(r2, r3);
    wv.z = pack2(r4, r5); wv.w = pack2(r6, r7);
    *(uint4*)(out + o) = wv;
  }
}

__device__ __forceinline__ void gemm_phase(
    const unsigned short* __restrict__ T0, const unsigned short* __restrict__ T1,
    const unsigned short* __restrict__ T2, const unsigned short* __restrict__ T3,
    const unsigned short* __restrict__ T4,
    const unsigned short* __restrict__ Wt, const float* __restrict__ bias,
    unsigned short* __restrict__ Hb,
    const float* __restrict__ linw, const float* __restrict__ linb,
    float* __restrict__ y, int M, int mode,
    unsigned short (*As)[72], unsigned short (*Bs)[72]) {
  const unsigned short* chunks[5] = {T0, T1, T2, T3, T4};
  int tid = threadIdx.x;
  int wave = tid >> 6, lane = tid & 63;
  int lrow = lane & 15, quad = lane >> 4;
  int ar = tid >> 2, aseg = (tid & 3) * 16;
  int bc = tid >> 1, bseg = (tid & 1) * 32;

  int tiles = (M + 63) >> 6;
  for (int tile = blockIdx.x; tile < tiles; tile += GBLK) {
    int rowBase = tile * 64;
    f32x4 acc[8];
#pragma unroll
    for (int b = 0; b < 8; ++b) acc[b] = (f32x4){0.f, 0.f, 0.f, 0.f};
    int agrow = min(rowBase + ar, M - 1);

    int4 aR0, aR1, bR0, bR1, bR2, bR3;
    {
      const unsigned short* ap = chunks[0] + (size_t)agrow * WID + aseg;
      aR0 = *(const int4*)ap;
      aR1 = *(const int4*)(ap + 8);
      const unsigned short* bp = Wt + (size_t)bc * 640 + bseg;
      bR0 = *(const int4*)bp;
      bR1 = *(const int4*)(bp + 8);
      bR2 = *(const int4*)(bp + 16);
      bR3 = *(const int4*)(bp + 24);
    }

    for (int kc = 0; kc < 10; ++kc) {
      *(int4*)(&As[ar][aseg]) = aR0;
      *(int4*)(&As[ar][aseg + 8]) = aR1;
      *(int4*)(&Bs[bc][bseg]) = bR0;
      *(int4*)(&Bs[bc][bseg + 8]) = bR1;
      *(int4*)(&Bs[bc][bseg + 16]) = bR2;
      *(int4*)(&Bs[bc][bseg + 24]) = bR3;
      __syncthreads();

      if (kc < 9) {
        int kn = kc + 1;
        const unsigned short* ap =
            chunks[kn >> 1] + (size_t)agrow * WID + (kn & 1) * 64 + aseg;
        aR0 = *(const int4*)ap;
        aR1 = *(const int4*)(ap + 8);
        const unsigned short* bp = Wt + (size_t)bc * 640 + kn * 64 + bseg;
        bR0 = *(const int4*)bp;
        bR1 = *(const int4*)(bp + 8);
        bR2 = *(const int4*)(bp + 16);
        bR3 = *(const int4*)(bp + 24);
      }

      bf16x8 a0 = *(bf16x8*)(&As[wave * 16 + lrow][quad * 8]);
      bf16x8 a1 = *(bf16x8*)(&As[wave * 16 + lrow][32 + quad * 8]);
#pragma unroll
      for (int ct = 0; ct < 8; ++ct) {
        bf16x8 b0 = *(bf16x8*)(&Bs[ct * 16 + lrow][quad * 8]);
        acc[ct] = __builtin_amdgcn_mfma_f32_16x16x32_bf16(a0, b0, acc[ct], 0, 0, 0);
        bf16x8 b1 = *(bf16x8*)(&Bs[ct * 16 + lrow][32 + quad * 8]);
        acc[ct] = __builtin_amdgcn_mfma_f32_16x16x32_bf16(a1, b1, acc[ct], 0, 0, 0);
      }
      __syncthreads();
    }

    if (mode != 2) {
#pragma unroll
      for (int ct = 0; ct < 8; ++ct) {
        int gcol = ct * 16 + lrow;
        float bv = bias[gcol];
#pragma unroll
        for (int reg = 0; reg < 4; ++reg) {
          int grow = rowBase + wave * 16 + quad * 4 + reg;
          if (grow < M) {
            float v = acc[ct][reg] + bv;
            v = fmaxf(v, 0.f);
            Hb[(size_t)grow * WID + gcol] = f2bf(v);
          }
        }
      }
    } else {
      float lwv[8], bvv[8];
#pragma unroll
      for (int ct = 0; ct < 8; ++ct) {
        int gcol = ct * 16 + lrow;
        lwv[ct] = linw[gcol];
        bvv[ct] = bias[gcol];
      }
#pragma unroll
      for (int reg = 0; reg < 4; ++reg) {
        float part = 0.f;
#pragma unroll
        for (int ct = 0; ct < 8; ++ct) part += (acc[ct][reg] + bvv[ct]) * lwv[ct];
#pragma unroll
        for (int off = 1; off < 16; off <<= 1) part += __shfl_xor(part, off, 16);
        int grow = rowBase + wave * 16 + quad * 4 + reg;
        if (lrow == 0 && grow < M) y[grow] = part + linb[0];
      }
    }
  }
}

// ---------------- mega-kernel: all 6 layers, hand-rolled grid barrier ----------------

__global__ __launch_bounds__(256, 4) void cheb_all(
    const unsigned short* __restrict__ Xbf,
    unsigned short* __restrict__ Hb0, unsigned short* __restrict__ Hb1,
    unsigned short* __restrict__ T1b, unsigned short* __restrict__ T2b,
    unsigned short* __restrict__ T3b, unsigned short* __restrict__ T4b,
    const unsigned short* __restrict__ Wt, const float* __restrict__ conv_b,
    const float* __restrict__ linw, const float* __restrict__ linb,
    const int* __restrict__ row_start, const int2* __restrict__ csr,
    int* __restrict__ bar_cnt, int* __restrict__ bar_gen,
    float* __restrict__ y, int n) {
  __shared__ unsigned short As[64][72];
  __shared__ unsigned short Bs[128][72];
  int gen = 0;

  for (int l = 0; l < 6; ++l) {
    const unsigned short* T0 = (l == 0) ? Xbf : ((l & 1) ? Hb0 : Hb1);
    unsigned short* Hb = (l & 1) ? Hb1 : Hb0;
    int mode = (l < 5) ? 1 : 2;

    prop_phase(T1b, T0, nullptr, 1.0f, row_start, csr, n);
    gsync(bar_cnt, bar_gen, gen);
    prop_phase(T2b, T1b, T0, 2.0f, row_start, csr, n);
    gsync(bar_cnt, bar_gen, gen);
    prop_phase(T3b, T2b, T1b, 2.0f, row_start, csr, n);
    gsync(bar_cnt, bar_gen, gen);
    prop_phase(T4b, T3b, T2b, 2.0f, row_start, csr, n);
    gsync(bar_cnt, bar_gen, gen);
    gemm_phase(T0, T1b, T2b, T3b, T4b, Wt + (size_t)l * WID * 640,
               conv_b + (size_t)l * WID, Hb, linw, linb, y, n, mode, As, Bs);
    if (l < 5) gsync(bar_cnt, bar_gen, gen);
  }
}

// ---------------- host orchestration ----------------

extern "C" void kernel_launch(void* const* d_in, const int* in_sizes, int n_in,
                              void* d_out, int out_size, void* d_ws, size_t ws_size,
                              hipStream_t stream) {
  const float* x = (const float*)d_in[0];
  const int* ei = (const int*)d_in[1];          // int32 per harness contract
  const float* conv_w = (const float*)d_in[2];  // [6][5][128][128]
  const float* conv_b = (const float*)d_in[3];  // [6][128]
  const float* lin_w = (const float*)d_in[4];   // [128]
  const float* lin_b = (const float*)d_in[5];   // [1]

  const int N = NN, E = NE, C = WID, L = 6;
  const int NB = (N + 255) / 256;

  char* ws = (char*)d_ws;
  size_t off = 0;
  auto alloc = [&](size_t bytes) -> void* {
    void* p = ws + off;
    off = (off + bytes + 255) & ~(size_t)255;
    return p;
  };
  int* deg = (int*)alloc((size_t)N * 4);
  float* dinv = (float*)alloc((size_t)N * 4);
  int* row_start = (int*)alloc((size_t)(N + 1) * 4);
  int* fill_ptr = (int*)alloc((size_t)N * 4);
  int* lex = (int*)alloc((size_t)N * 4);
  int* bsum = (int*)alloc((size_t)NB * 4);
  int* boff = (int*)alloc((size_t)NB * 4);
  int* bar = (int*)alloc(256);                 // [0]=count, [1]=gen_done
  int2* csr = (int2*)alloc((size_t)E * 8);
  unsigned short* Xbf = (unsigned short*)alloc((size_t)N * C * 2);
  unsigned short* Hb0 = (unsigned short*)alloc((size_t)N * C * 2);
  unsigned short* Hb1 = (unsigned short*)alloc((size_t)N * C * 2);
  unsigned short* T1b = (unsigned short*)alloc((size_t)N * C * 2);
  unsigned short* T2b = (unsigned short*)alloc((size_t)N * C * 2);
  unsigned short* T3b = (unsigned short*)alloc((size_t)N * C * 2);
  unsigned short* T4b = (unsigned short*)alloc((size_t)N * C * 2);
  unsigned short* Wt = (unsigned short*)alloc((size_t)L * C * 640 * 2);

  // preprocessing
  hipMemsetAsync(deg, 0, (size_t)N * 4, stream);
  hipMemsetAsync(bar, 0, 256, stream);
  degree_kernel<<<(E + 255) / 256, 256, 0, stream>>>(ei, deg, E);
  scan1_kernel<<<NB, 256, 0, stream>>>(deg, lex, bsum, dinv, N);
  scan2_kernel<<<1, 256, 0, stream>>>(bsum, boff, &row_start[N], NB);
  scan3_kernel<<<NB, 256, 0, stream>>>(lex, boff, row_start, fill_ptr, N);
  fill_kernel<<<(E + 255) / 256, 256, 0, stream>>>(ei, dinv, fill_ptr, csr, E);
  cvt_x_kernel<<<(N * C + 255) / 256, 256, 0, stream>>>(x, Xbf, N * C);
  cvt_w_kernel<<<(L * C * 640 + 255) / 256, 256, 0, stream>>>(conv_w, Wt, L * C * 640);

  // all 6 layers in one plain launch (1024 blocks, guaranteed co-resident at 4/CU)
  cheb_all<<<GBLK, 256, 0, stream>>>(Xbf, Hb0, Hb1, T1b, T2b, T3b, T4b, Wt, conv_b,
                                     lin_w, lin_b, row_start, csr, &bar[0], &bar[1],
                                     (float*)d_out, N);
}

// Round 14
// 915.047 us; speedup vs baseline: 11.6844x; 11.6844x over previous
//
#include <hip/hip_runtime.h>

// ChebConv GNN: 6 layers x (K=5 Chebyshev), 50000 nodes / 640000 edges, WIDTH=128.
//  - CSR packed to 4B/edge: {src:20 | exp4 | mant8} (norm = -m*2^(e-112), 8-bit mantissa
//    ~0.1% rel err, below the bf16 feature error). Halves csr stream + fill write-alloc.
//  - All Chebyshev T_k stored bf16; prop: 16 lanes/node, uint4 (8ch) gathers,
//    shfl-broadcast packed descriptors, 4-deep unroll (R11: 8-deep regresses).
//  - cheb_gemm: LDS-staged 64x128 tile, BK=64, register prefetch; final layer fuses
//    Linear(128->1) via shfl_xor reduce.
//  NOTE (R9): __builtin_nontemporal_* scalarizes vector accesses on gfx950 - avoid.
//  NOTE (R12/13): cooperative launch no-ops; software grid barriers cost 10x (L2
//  flush + spin convoys). Separate kernel launches are the cheap sync on MI355X.

#define NN 50000
#define NE 640000
#define WID 128

typedef __attribute__((ext_vector_type(8))) short bf16x8;
typedef __attribute__((ext_vector_type(4))) float f32x4;

__device__ __forceinline__ unsigned short f2bf(float f) {
  union { float f; unsigned int u; } v; v.f = f;
  unsigned int r = v.u + 0x7FFF + ((v.u >> 16) & 1);  // RNE
  return (unsigned short)(r >> 16);
}
__device__ __forceinline__ unsigned int pack2(float lo, float hi) {
  return (unsigned int)f2bf(lo) | ((unsigned int)f2bf(hi) << 16);
}
__device__ __forceinline__ float bflo(unsigned int u) {
  return __uint_as_float(u << 16);
}
__device__ __forceinline__ float bfhi(unsigned int u) {
  return __uint_as_float(u & 0xffff0000u);
}
// decode packed edge: norm magnitude (negative applied): bits 11..8 = exp-112, 7..0 = mant
__device__ __forceinline__ float dec_norm(unsigned int p) {
  unsigned int lo = p & 0xfffu;
  float v = -__uint_as_float(((112u + ((p >> 8) & 15u)) << 23) | ((p & 255u) << 15));
  return (lo == 0u) ? 0.f : v;
}

// ---------------- preprocessing ----------------

__global__ __launch_bounds__(256) void degree_kernel(const int* __restrict__ ei,
                                                     int* __restrict__ deg, int E) {
  int e = blockIdx.x * 256 + threadIdx.x;
  if (e < E) atomicAdd(&deg[ei[E + e]], 1);
}

// per-block scan of deg + block sums; also emits dinv = rsqrt(deg)
__global__ __launch_bounds__(256) void scan1_kernel(const int* __restrict__ deg,
                                                    int* __restrict__ lex,
                                                    int* __restrict__ bsum,
                                                    float* __restrict__ dinv, int n) {
  __shared__ int ws[4];
  int tid = threadIdx.x, lane = tid & 63, w = tid >> 6;
  int i = blockIdx.x * 256 + tid;
  int cnt = (i < n) ? deg[i] : 0;
  if (i < n) {
    float d = (float)cnt;
    dinv[i] = d > 0.0f ? rsqrtf(d) : 0.0f;
  }
  int v = cnt;
#pragma unroll
  for (int off = 1; off < 64; off <<= 1) {
    int u = __shfl_up(v, off, 64);
    if (lane >= off) v += u;
  }
  if (lane == 63) ws[w] = v;
  __syncthreads();
  int wexcl = 0;
#pragma unroll
  for (int k = 0; k < 4; ++k) wexcl += (k < w) ? ws[k] : 0;
  if (i < n) lex[i] = wexcl + v - cnt;
  if (tid == 255) bsum[blockIdx.x] = wexcl + v;
}

__global__ __launch_bounds__(256) void scan2_kernel(const int* __restrict__ bsum,
                                                    int* __restrict__ boff,
                                                    int* __restrict__ row_end, int nb) {
  __shared__ int ws[4];
  int tid = threadIdx.x, lane = tid & 63, w = tid >> 6;
  int cnt = (tid < nb) ? bsum[tid] : 0;
  int v = cnt;
#pragma unroll
  for (int off = 1; off < 64; off <<= 1) {
    int u = __shfl_up(v, off, 64);
    if (lane >= off) v += u;
  }
  if (lane == 63) ws[w] = v;
  __syncthreads();
  int wexcl = 0;
#pragma unroll
  for (int k = 0; k < 4; ++k) wexcl += (k < w) ? ws[k] : 0;
  if (tid < nb) boff[tid] = wexcl + v - cnt;
  if (tid == 255) *row_end = wexcl + v;
}

__global__ __launch_bounds__(256) void scan3_kernel(const int* __restrict__ lex,
                                                    const int* __restrict__ boff,
                                                    int* __restrict__ row_start,
                                                    int* __restrict__ fill_ptr, int n) {
  int i = blockIdx.x * 256 + threadIdx.x;
  if (i < n) {
    int rs = lex[i] + boff[blockIdx.x];
    row_start[i] = rs;
    fill_ptr[i] = rs;
  }
}

__global__ __launch_bounds__(256) void fill_kernel(const int* __restrict__ ei,
                                                   const float* __restrict__ dinv,
                                                   int* __restrict__ fill_ptr,
                                                   unsigned int* __restrict__ csr, int E) {
  int e = blockIdx.x * 256 + threadIdx.x;
  if (e < E) {
    int s = ei[e];
    int d = ei[E + e];
    int pos = atomicAdd(&fill_ptr[d], 1);
    float mag = dinv[s] * dinv[d];
    unsigned int bits = __float_as_uint(mag);
    unsigned int pk = (unsigned int)s << 12;
    if (bits != 0u) {
      bits += 0x4000u;  // round at bit 15 (carry propagates into exponent)
      int ex = (int)((bits >> 23) & 255u) - 112;
      ex = max(0, min(15, ex));
      pk |= ((unsigned int)ex << 8) | ((bits >> 15) & 0xffu);
    }
    csr[pos] = pk;
  }
}

// merged: x fp32 -> bf16 (first nx elems) and conv_w transpose -> Wt bf16 (next nw)
__global__ __launch_bounds__(256) void cvt_kernel(const float* __restrict__ x,
                                                  unsigned short* __restrict__ xo,
                                                  const float* __restrict__ w,
                                                  unsigned short* __restrict__ wt,
                                                  int nx, int nw) {
  int i = blockIdx.x * 256 + threadIdx.x;
  if (i < nx) {
    xo[i] = f2bf(x[i]);
  } else if (i < nx + nw) {
    int j = i - nx;
    int l = j / (WID * 640);
    int r = j % (WID * 640);
    int col = r / 640;
    int k = r % 640;
    int kk = k >> 7, m = k & 127;
    wt[j] = f2bf(w[(((size_t)l * 5 + kk) * WID + m) * WID + col]);
  }
}

// ---------------- propagate: out(bf16) = scale * (L_hat @ xin(bf16)) - sub(bf16) ----------
// 16 lanes/node (16B = 8ch per lane), 16 nodes per 256-thr block. Lanes cooperatively
// prefetch up to 16 packed edge descriptors (4B each, one coalesced dword), broadcast
// via shfl(w=16), gathers 4-unrolled. fp32 accumulate. (R7/R10-proven shape)

__global__ __launch_bounds__(256) void prop_kernel(unsigned short* __restrict__ out,
                                                   const unsigned short* __restrict__ xin,
                                                   const unsigned short* __restrict__ sub,
                                                   float scale,
                                                   const int* __restrict__ row_start,
                                                   const unsigned int* __restrict__ csr,
                                                   int n) {
  int node = blockIdx.x * 16 + (threadIdx.x >> 4);
  if (node >= n) return;
  int t = threadIdx.x & 15;
  int s = row_start[node], e = row_start[node + 1];
  float a0 = 0.f, a1 = 0.f, a2 = 0.f, a3 = 0.f;
  float a4 = 0.f, a5 = 0.f, a6 = 0.f, a7 = 0.f;
  for (int base = s; base < e; base += 16) {
    int cnt = min(16, e - base);
    unsigned int ed = (t < cnt) ? csr[base + t] : 0u;
    int j = 0;
    for (; j + 4 <= cnt; j += 4) {
      unsigned int p0 = (unsigned int)__shfl((int)ed, j, 16);
      unsigned int p1 = (unsigned int)__shfl((int)ed, j + 1, 16);
      unsigned int p2 = (unsigned int)__shfl((int)ed, j + 2, 16);
      unsigned int p3 = (unsigned int)__shfl((int)ed, j + 3, 16);
      int s0 = p0 >> 12, s1 = p1 >> 12, s2 = p2 >> 12, s3 = p3 >> 12;
      float n0 = dec_norm(p0), n1 = dec_norm(p1), n2 = dec_norm(p2), n3 = dec_norm(p3);
      const uint4 v0 = *(const uint4*)(xin + (size_t)s0 * WID + t * 8);
      const uint4 v1 = *(const uint4*)(xin + (size_t)s1 * WID + t * 8);
      const uint4 v2 = *(const uint4*)(xin + (size_t)s2 * WID + t * 8);
      const uint4 v3 = *(const uint4*)(xin + (size_t)s3 * WID + t * 8);
      a0 += n0 * bflo(v0.x) + n1 * bflo(v1.x) + n2 * bflo(v2.x) + n3 * bflo(v3.x);
      a1 += n0 * bfhi(v0.x) + n1 * bfhi(v1.x) + n2 * bfhi(v2.x) + n3 * bfhi(v3.x);
      a2 += n0 * bflo(v0.y) + n1 * bflo(v1.y) + n2 * bflo(v2.y) + n3 * bflo(v3.y);
      a3 += n0 * bfhi(v0.y) + n1 * bfhi(v1.y) + n2 * bfhi(v2.y) + n3 * bfhi(v3.y);
      a4 += n0 * bflo(v0.z) + n1 * bflo(v1.z) + n2 * bflo(v2.z) + n3 * bflo(v3.z);
      a5 += n0 * bfhi(v0.z) + n1 * bfhi(v1.z) + n2 * bfhi(v2.z) + n3 * bfhi(v3.z);
      a6 += n0 * bflo(v0.w) + n1 * bflo(v1.w) + n2 * bflo(v2.w) + n3 * bflo(v3.w);
      a7 += n0 * bfhi(v0.w) + n1 * bfhi(v1.w) + n2 * bfhi(v2.w) + n3 * bfhi(v3.w);
    }
    for (; j < cnt; ++j) {
      unsigned int pj = (unsigned int)__shfl((int)ed, j, 16);
      int sj = pj >> 12;
      float nj = dec_norm(pj);
      const uint4 v = *(const uint4*)(xin + (size_t)sj * WID + t * 8);
      a0 += nj * bflo(v.x); a1 += nj * bfhi(v.x);
      a2 += nj * bflo(v.y); a3 += nj * bfhi(v.y);
      a4 += nj * bflo(v.z); a5 += nj * bfhi(v.z);
      a6 += nj * bflo(v.w); a7 += nj * bfhi(v.w);
    }
  }
  size_t o = (size_t)node * WID + t * 8;
  float r0 = scale * a0, r1 = scale * a1, r2 = scale * a2, r3 = scale * a3;
  float r4 = scale * a4, r5 = scale * a5, r6 = scale * a6, r7 = scale * a7;
  if (sub) {
    const uint4 sv = *(const uint4*)(sub + o);
    r0 -= bflo(sv.x); r1 -= bfhi(sv.x);
    r2 -= bflo(sv.y); r3 -= bfhi(sv.y);
    r4 -= bflo(sv.z); r5 -= bfhi(sv.z);
    r6 -= bflo(sv.w); r7 -= bfhi(sv.w);
  }
  uint4 wv;
  wv.x = pack2(r0, r1); wv.y = pack2(r2, r3);
  wv.z = pack2(r4, r5); wv.w = pack2(r6, r7);
  *(uint4*)(out + o) = wv;
}

// ---------------- fused layer GEMM: H[N,128] = A[N,640](bf16) @ W[640,128] + b ----------
// 256 thr = 4 waves; block tile 64 rows x 128 cols (wave w: rows w*16..w*16+15).
// BK=64, 10 k-chunks, LDS As[64][72] + Bs[128][72] (27.6 KB). Register prefetch of
// chunk kc+1 issued after barrier1; 16 MFMAs per stage hide it.
// mode: 1 = ReLU + write bf16 Hb; 2 = final -> fuse Linear(128->1), write y fp32.

__global__ __launch_bounds__(256) void cheb_gemm(
    const unsigned short* __restrict__ T0, const unsigned short* __restrict__ T1,
    const unsigned short* __restrict__ T2, const unsigned short* __restrict__ T3,
    const unsigned short* __restrict__ T4,
    const unsigned short* __restrict__ Wt,
    const float* __restrict__ bias,
    unsigned short* __restrict__ Hb,
    const float* __restrict__ linw, const float* __restrict__ linb,
    float* __restrict__ y, int M, int mode) {
  __shared__ unsigned short As[64][72];   // [row][k 0..63], pad to 72
  __shared__ unsigned short Bs[128][72];  // [col][k 0..63]
  const unsigned short* chunks[5] = {T0, T1, T2, T3, T4};
  int tid = threadIdx.x;
  int wave = tid >> 6, lane = tid & 63;
  int lrow = lane & 15, quad = lane >> 4;
  int rowBase = blockIdx.x * 64;

  f32x4 acc[8];
#pragma unroll
  for (int b = 0; b < 8; ++b) acc[b] = (f32x4){0.f, 0.f, 0.f, 0.f};

  // staging coords
  int ar = tid >> 2, aseg = (tid & 3) * 16;         // A: row 0..63, 16-short seg (2x int4)
  int agrow = min(rowBase + ar, M - 1);             // clamp (garbage rows never stored)
  int bc = tid >> 1, bseg = (tid & 1) * 32;         // B: col 0..127, 32-short seg (4x int4)

  int4 aR0, aR1, bR0, bR1, bR2, bR3;
  {
    const unsigned short* ap = chunks[0] + (size_t)agrow * WID + aseg;
    aR0 = *(const int4*)ap;
    aR1 = *(const int4*)(ap + 8);
    const unsigned short* bp = Wt + (size_t)bc * 640 + bseg;
    bR0 = *(const int4*)bp;
    bR1 = *(const int4*)(bp + 8);
    bR2 = *(const int4*)(bp + 16);
    bR3 = *(const int4*)(bp + 24);
  }

  for (int kc = 0; kc < 10; ++kc) {
    *(int4*)(&As[ar][aseg]) = aR0;
    *(int4*)(&As[ar][aseg + 8]) = aR1;
    *(int4*)(&Bs[bc][bseg]) = bR0;
    *(int4*)(&Bs[bc][bseg + 8]) = bR1;
    *(int4*)(&Bs[bc][bseg + 16]) = bR2;
    *(int4*)(&Bs[bc][bseg + 24]) = bR3;
    __syncthreads();

    if (kc < 9) {  // prefetch next chunk; overlaps the 16 MFMAs below
      int kn = kc + 1;
      const unsigned short* ap =
          chunks[kn >> 1] + (size_t)agrow * WID + (kn & 1) * 64 + aseg;
      aR0 = *(const int4*)ap;
      aR1 = *(const int4*)(ap + 8);
      const unsigned short* bp = Wt + (size_t)bc * 640 + kn * 64 + bseg;
      bR0 = *(const int4*)bp;
      bR1 = *(const int4*)(bp + 8);
      bR2 = *(const int4*)(bp + 16);
      bR3 = *(const int4*)(bp + 24);
    }

    bf16x8 a0 = *(bf16x8*)(&As[wave * 16 + lrow][quad * 8]);
    bf16x8 a1 = *(bf16x8*)(&As[wave * 16 + lrow][32 + quad * 8]);
#pragma unroll
    for (int ct = 0; ct < 8; ++ct) {
      bf16x8 b0 = *(bf16x8*)(&Bs[ct * 16 + lrow][quad * 8]);
      acc[ct] = __builtin_amdgcn_mfma_f32_16x16x32_bf16(a0, b0, acc[ct], 0, 0, 0);
      bf16x8 b1 = *(bf16x8*)(&Bs[ct * 16 + lrow][32 + quad * 8]);
      acc[ct] = __builtin_amdgcn_mfma_f32_16x16x32_bf16(a1, b1, acc[ct], 0, 0, 0);
    }
    __syncthreads();
  }

  // epilogue: C/D layout col=lane&15, row=quad*4+reg ; wave rows rowBase+wave*16+...
  if (mode != 2) {
#pragma unroll
    for (int ct = 0; ct < 8; ++ct) {
      int gcol = ct * 16 + lrow;
      float bv = bias[gcol];
#pragma unroll
      for (int reg = 0; reg < 4; ++reg) {
        int grow = rowBase + wave * 16 + quad * 4 + reg;
        if (grow < M) {
          float v = acc[ct][reg] + bv;
          if (mode == 1) v = fmaxf(v, 0.f);
          Hb[(size_t)grow * WID + gcol] = f2bf(v);
        }
      }
    }
  } else {
    // final layer: y[row] = sum_col (acc+bias)[col] * linw[col] + linb
    float lwv[8], bvv[8];
#pragma unroll
    for (int ct = 0; ct < 8; ++ct) {
      int gcol = ct * 16 + lrow;
      lwv[ct] = linw[gcol];
      bvv[ct] = bias[gcol];
    }
#pragma unroll
    for (int reg = 0; reg < 4; ++reg) {
      float part = 0.f;
#pragma unroll
      for (int ct = 0; ct < 8; ++ct) part += (acc[ct][reg] + bvv[ct]) * lwv[ct];
#pragma unroll
      for (int off = 1; off < 16; off <<= 1) part += __shfl_xor(part, off, 16);
      int grow = rowBase + wave * 16 + quad * 4 + reg;
      if (lrow == 0 && grow < M) y[grow] = part + linb[0];
    }
  }
}

// ---------------- host orchestration ----------------

extern "C" void kernel_launch(void* const* d_in, const int* in_sizes, int n_in,
                              void* d_out, int out_size, void* d_ws, size_t ws_size,
                              hipStream_t stream) {
  const float* x = (const float*)d_in[0];
  const int* ei = (const int*)d_in[1];          // int32 per harness contract
  const float* conv_w = (const float*)d_in[2];  // [6][5][128][128]
  const float* conv_b = (const float*)d_in[3];  // [6][128]
  const float* lin_w = (const float*)d_in[4];   // [128]
  const float* lin_b = (const float*)d_in[5];   // [1]

  const int N = NN, E = NE, C = WID, L = 6;
  const int NB = (N + 255) / 256;

  char* ws = (char*)d_ws;
  size_t off = 0;
  auto alloc = [&](size_t bytes) -> void* {
    void* p = ws + off;
    off = (off + bytes + 255) & ~(size_t)255;
    return p;
  };
  int* deg = (int*)alloc((size_t)N * 4);
  float* dinv = (float*)alloc((size_t)N * 4);
  int* row_start = (int*)alloc((size_t)(N + 1) * 4);
  int* fill_ptr = (int*)alloc((size_t)N * 4);
  int* lex = (int*)alloc((size_t)N * 4);
  int* bsum = (int*)alloc((size_t)NB * 4);
  int* boff = (int*)alloc((size_t)NB * 4);
  unsigned int* csr = (unsigned int*)alloc((size_t)E * 4);
  unsigned short* Xbf = (unsigned short*)alloc((size_t)N * C * 2);
  unsigned short* Hb0 = (unsigned short*)alloc((size_t)N * C * 2);
  unsigned short* Hb1 = (unsigned short*)alloc((size_t)N * C * 2);
  unsigned short* T1b = (unsigned short*)alloc((size_t)N * C * 2);
  unsigned short* T2b = (unsigned short*)alloc((size_t)N * C * 2);
  unsigned short* T3b = (unsigned short*)alloc((size_t)N * C * 2);
  unsigned short* T4b = (unsigned short*)alloc((size_t)N * C * 2);
  unsigned short* Wt = (unsigned short*)alloc((size_t)L * C * 640 * 2);

  // preprocessing
  hipMemsetAsync(deg, 0, (size_t)N * 4, stream);
  degree_kernel<<<(E + 255) / 256, 256, 0, stream>>>(ei, deg, E);
  scan1_kernel<<<NB, 256, 0, stream>>>(deg, lex, bsum, dinv, N);
  scan2_kernel<<<1, 256, 0, stream>>>(bsum, boff, &row_start[N], NB);
  scan3_kernel<<<NB, 256, 0, stream>>>(lex, boff, row_start, fill_ptr, N);
  fill_kernel<<<(E + 255) / 256, 256, 0, stream>>>(ei, dinv, fill_ptr, csr, E);
  {
    int nx = N * C, nw = L * C * 640;
    cvt_kernel<<<(nx + nw + 255) / 256, 256, 0, stream>>>(x, Xbf, conv_w, Wt, nx, nw);
  }

  const int pg = (N + 15) / 16;     // prop grid (16 nodes/block)
  const int gg = (N + 63) / 64;     // gemm grid (64 rows/block)

  for (int l = 0; l < L; ++l) {
    const unsigned short* T0 = (l == 0) ? Xbf : ((l & 1) ? Hb0 : Hb1);
    unsigned short* Hb = (l & 1) ? Hb1 : Hb0;
    int mode = (l < L - 1) ? 1 : 2;   // 1 = ReLU->Hb, 2 = final fused linear -> y

    prop_kernel<<<pg, 256, 0, stream>>>(T1b, T0, nullptr, 1.0f, row_start, csr, N);
    prop_kernel<<<pg, 256, 0, stream>>>(T2b, T1b, T0, 2.0f, row_start, csr, N);
    prop_kernel<<<pg, 256, 0, stream>>>(T3b, T2b, T1b, 2.0f, row_start, csr, N);
    prop_kernel<<<pg, 256, 0, stream>>>(T4b, T3b, T2b, 2.0f, row_start, csr, N);
    cheb_gemm<<<gg, 256, 0, stream>>>(T0, T1b, T2b, T3b, T4b,
                                      Wt + (size_t)l * C * 640, conv_b + (size_t)l * C,
                                      Hb, lin_w, lin_b, (float*)d_out, N, mode);
  }
}

// Round 15
// 905.204 us; speedup vs baseline: 11.8114x; 1.0109x over previous
//
#include <hip/hip_runtime.h>

// ChebConv GNN: 6 layers x (K=5 Chebyshev), 50000 nodes / 640000 edges, WIDTH=128.
//  - CSR packed to 4B/edge: {src:20 | exp4 | mant8} (norm = -m*2^(e-112)).
//  - All Chebyshev T_k stored bf16; prop: GRID-STRIDE 2048 blocks (8/CU resident,
//    no dispatch ramp/tail), 16 lanes/node, uint4 gathers, shfl-broadcast packed
//    descriptors, 4-deep unroll (R11: 8-deep regresses). fp32 accumulate.
//  - cheb_gemm: LDS-staged 64x128 tile, BK=64, register prefetch; final layer fuses
//    Linear(128->1) via shfl_xor reduce.
//  NOTE (R9): __builtin_nontemporal_* scalarizes vector accesses on gfx950 - avoid.
//  NOTE (R12/13): cooperative launch no-ops; software grid barriers cost 10x.

#define NN 50000
#define NE 640000
#define WID 128
#define PROP_BLOCKS 2048

typedef __attribute__((ext_vector_type(8))) short bf16x8;
typedef __attribute__((ext_vector_type(4))) float f32x4;

__device__ __forceinline__ unsigned short f2bf(float f) {
  union { float f; unsigned int u; } v; v.f = f;
  unsigned int r = v.u + 0x7FFF + ((v.u >> 16) & 1);  // RNE
  return (unsigned short)(r >> 16);
}
__device__ __forceinline__ unsigned int pack2(float lo, float hi) {
  return (unsigned int)f2bf(lo) | ((unsigned int)f2bf(hi) << 16);
}
__device__ __forceinline__ float bflo(unsigned int u) {
  return __uint_as_float(u << 16);
}
__device__ __forceinline__ float bfhi(unsigned int u) {
  return __uint_as_float(u & 0xffff0000u);
}
// decode packed edge: bits 11..8 = exp-112, 7..0 = mant (norm is negative)
__device__ __forceinline__ float dec_norm(unsigned int p) {
  unsigned int lo = p & 0xfffu;
  float v = -__uint_as_float(((112u + ((p >> 8) & 15u)) << 23) | ((p & 255u) << 15));
  return (lo == 0u) ? 0.f : v;
}

// ---------------- preprocessing ----------------

__global__ __launch_bounds__(256) void degree_kernel(const int* __restrict__ ei,
                                                     int* __restrict__ deg, int E) {
  int e = blockIdx.x * 256 + threadIdx.x;
  if (e < E) atomicAdd(&deg[ei[E + e]], 1);
}

__global__ __launch_bounds__(256) void scan1_kernel(const int* __restrict__ deg,
                                                    int* __restrict__ lex,
                                                    int* __restrict__ bsum,
                                                    float* __restrict__ dinv, int n) {
  __shared__ int ws[4];
  int tid = threadIdx.x, lane = tid & 63, w = tid >> 6;
  int i = blockIdx.x * 256 + tid;
  int cnt = (i < n) ? deg[i] : 0;
  if (i < n) {
    float d = (float)cnt;
    dinv[i] = d > 0.0f ? rsqrtf(d) : 0.0f;
  }
  int v = cnt;
#pragma unroll
  for (int off = 1; off < 64; off <<= 1) {
    int u = __shfl_up(v, off, 64);
    if (lane >= off) v += u;
  }
  if (lane == 63) ws[w] = v;
  __syncthreads();
  int wexcl = 0;
#pragma unroll
  for (int k = 0; k < 4; ++k) wexcl += (k < w) ? ws[k] : 0;
  if (i < n) lex[i] = wexcl + v - cnt;
  if (tid == 255) bsum[blockIdx.x] = wexcl + v;
}

__global__ __launch_bounds__(256) void scan2_kernel(const int* __restrict__ bsum,
                                                    int* __restrict__ boff,
                                                    int* __restrict__ row_end, int nb) {
  __shared__ int ws[4];
  int tid = threadIdx.x, lane = tid & 63, w = tid >> 6;
  int cnt = (tid < nb) ? bsum[tid] : 0;
  int v = cnt;
#pragma unroll
  for (int off = 1; off < 64; off <<= 1) {
    int u = __shfl_up(v, off, 64);
    if (lane >= off) v += u;
  }
  if (lane == 63) ws[w] = v;
  __syncthreads();
  int wexcl = 0;
#pragma unroll
  for (int k = 0; k < 4; ++k) wexcl += (k < w) ? ws[k] : 0;
  if (tid < nb) boff[tid] = wexcl + v - cnt;
  if (tid == 255) *row_end = wexcl + v;
}

__global__ __launch_bounds__(256) void scan3_kernel(const int* __restrict__ lex,
                                                    const int* __restrict__ boff,
                                                    int* __restrict__ row_start,
                                                    int* __restrict__ fill_ptr, int n) {
  int i = blockIdx.x * 256 + threadIdx.x;
  if (i < n) {
    int rs = lex[i] + boff[blockIdx.x];
    row_start[i] = rs;
    fill_ptr[i] = rs;
  }
}

__global__ __launch_bounds__(256) void fill_kernel(const int* __restrict__ ei,
                                                   const float* __restrict__ dinv,
                                                   int* __restrict__ fill_ptr,
                                                   unsigned int* __restrict__ csr, int E) {
  int e = blockIdx.x * 256 + threadIdx.x;
  if (e < E) {
    int s = ei[e];
    int d = ei[E + e];
    int pos = atomicAdd(&fill_ptr[d], 1);
    float mag = dinv[s] * dinv[d];
    unsigned int bits = __float_as_uint(mag);
    unsigned int pk = (unsigned int)s << 12;
    if (bits != 0u) {
      bits += 0x4000u;  // round at bit 15 (carry propagates into exponent)
      int ex = (int)((bits >> 23) & 255u) - 112;
      ex = max(0, min(15, ex));
      pk |= ((unsigned int)ex << 8) | ((bits >> 15) & 0xffu);
    }
    csr[pos] = pk;
  }
}

// merged: x fp32 -> bf16 (first nx elems) and conv_w transpose -> Wt bf16 (next nw)
__global__ __launch_bounds__(256) void cvt_kernel(const float* __restrict__ x,
                                                  unsigned short* __restrict__ xo,
                                                  const float* __restrict__ w,
                                                  unsigned short* __restrict__ wt,
                                                  int nx, int nw) {
  int i = blockIdx.x * 256 + threadIdx.x;
  if (i < nx) {
    xo[i] = f2bf(x[i]);
  } else if (i < nx + nw) {
    int j = i - nx;
    int l = j / (WID * 640);
    int r = j % (WID * 640);
    int col = r / 640;
    int k = r % 640;
    int kk = k >> 7, m = k & 127;
    wt[j] = f2bf(w[(((size_t)l * 5 + kk) * WID + m) * WID + col]);
  }
}

// ---------------- propagate: out(bf16) = scale * (L_hat @ xin(bf16)) - sub(bf16) ----------
// Grid-stride over nodes with PROP_BLOCKS blocks (8/CU resident, no dispatch ramp).
// 16 lanes/node (16B = 8ch per lane), 16 node-slots per 256-thr block.

__global__ __launch_bounds__(256) void prop_kernel(unsigned short* __restrict__ out,
                                                   const unsigned short* __restrict__ xin,
                                                   const unsigned short* __restrict__ sub,
                                                   float scale,
                                                   const int* __restrict__ row_start,
                                                   const unsigned int* __restrict__ csr,
                                                   int n) {
  int t = threadIdx.x & 15;
  for (int node = blockIdx.x * 16 + (threadIdx.x >> 4); node < n;
       node += PROP_BLOCKS * 16) {
    int s = row_start[node], e = row_start[node + 1];
    float a0 = 0.f, a1 = 0.f, a2 = 0.f, a3 = 0.f;
    float a4 = 0.f, a5 = 0.f, a6 = 0.f, a7 = 0.f;
    for (int base = s; base < e; base += 16) {
      int cnt = min(16, e - base);
      unsigned int ed = (t < cnt) ? csr[base + t] : 0u;
      int j = 0;
      for (; j + 4 <= cnt; j += 4) {
        unsigned int p0 = (unsigned int)__shfl((int)ed, j, 16);
        unsigned int p1 = (unsigned int)__shfl((int)ed, j + 1, 16);
        unsigned int p2 = (unsigned int)__shfl((int)ed, j + 2, 16);
        unsigned int p3 = (unsigned int)__shfl((int)ed, j + 3, 16);
        int s0 = p0 >> 12, s1 = p1 >> 12, s2 = p2 >> 12, s3 = p3 >> 12;
        float n0 = dec_norm(p0), n1 = dec_norm(p1), n2 = dec_norm(p2), n3 = dec_norm(p3);
        const uint4 v0 = *(const uint4*)(xin + (size_t)s0 * WID + t * 8);
        const uint4 v1 = *(const uint4*)(xin + (size_t)s1 * WID + t * 8);
        const uint4 v2 = *(const uint4*)(xin + (size_t)s2 * WID + t * 8);
        const uint4 v3 = *(const uint4*)(xin + (size_t)s3 * WID + t * 8);
        a0 += n0 * bflo(v0.x) + n1 * bflo(v1.x) + n2 * bflo(v2.x) + n3 * bflo(v3.x);
        a1 += n0 * bfhi(v0.x) + n1 * bfhi(v1.x) + n2 * bfhi(v2.x) + n3 * bfhi(v3.x);
        a2 += n0 * bflo(v0.y) + n1 * bflo(v1.y) + n2 * bflo(v2.y) + n3 * bflo(v3.y);
        a3 += n0 * bfhi(v0.y) + n1 * bfhi(v1.y) + n2 * bfhi(v2.y) + n3 * bfhi(v3.y);
        a4 += n0 * bflo(v0.z) + n1 * bflo(v1.z) + n2 * bflo(v2.z) + n3 * bflo(v3.z);
        a5 += n0 * bfhi(v0.z) + n1 * bfhi(v1.z) + n2 * bfhi(v2.z) + n3 * bfhi(v3.z);
        a6 += n0 * bflo(v0.w) + n1 * bflo(v1.w) + n2 * bflo(v2.w) + n3 * bflo(v3.w);
        a7 += n0 * bfhi(v0.w) + n1 * bfhi(v1.w) + n2 * bfhi(v2.w) + n3 * bfhi(v3.w);
      }
      for (; j < cnt; ++j) {
        unsigned int pj = (unsigned int)__shfl((int)ed, j, 16);
        int sj = pj >> 12;
        float nj = dec_norm(pj);
        const uint4 v = *(const uint4*)(xin + (size_t)sj * WID + t * 8);
        a0 += nj * bflo(v.x); a1 += nj * bfhi(v.x);
        a2 += nj * bflo(v.y); a3 += nj * bfhi(v.y);
        a4 += nj * bflo(v.z); a5 += nj * bfhi(v.z);
        a6 += nj * bflo(v.w); a7 += nj * bfhi(v.w);
      }
    }
    size_t o = (size_t)node * WID + t * 8;
    float r0 = scale * a0, r1 = scale * a1, r2 = scale * a2, r3 = scale * a3;
    float r4 = scale * a4, r5 = scale * a5, r6 = scale * a6, r7 = scale * a7;
    if (sub) {
      const uint4 sv = *(const uint4*)(sub + o);
      r0 -= bflo(sv.x); r1 -= bfhi(sv.x);
      r2 -= bflo(sv.y); r3 -= bfhi(sv.y);
      r4 -= bflo(sv.z); r5 -= bfhi(sv.z);
      r6 -= bflo(sv.w); r7 -= bfhi(sv.w);
    }
    uint4 wv;
    wv.x = pack2(r0, r1); wv.y = pack2(r2, r3);
    wv.z = pack2(r4, r5); wv.w = pack2(r6, r7);
    *(uint4*)(out + o) = wv;
  }
}

// ---------------- fused layer GEMM: H[N,128] = A[N,640](bf16) @ W[640,128] + b ----------
// 256 thr = 4 waves; block tile 64 rows x 128 cols (wave w: rows w*16..w*16+15).
// BK=64, 10 k-chunks, LDS As[64][72] + Bs[128][72] (27.6 KB). Register prefetch of
// chunk kc+1 issued after barrier1; 16 MFMAs per stage hide it.
// mode: 1 = ReLU + write bf16 Hb; 2 = final -> fuse Linear(128->1), write y fp32.

__global__ __launch_bounds__(256) void cheb_gemm(
    const unsigned short* __restrict__ T0, const unsigned short* __restrict__ T1,
    const unsigned short* __restrict__ T2, const unsigned short* __restrict__ T3,
    const unsigned short* __restrict__ T4,
    const unsigned short* __restrict__ Wt,
    const float* __restrict__ bias,
    unsigned short* __restrict__ Hb,
    const float* __restrict__ linw, const float* __restrict__ linb,
    float* __restrict__ y, int M, int mode) {
  __shared__ unsigned short As[64][72];   // [row][k 0..63], pad to 72
  __shared__ unsigned short Bs[128][72];  // [col][k 0..63]
  const unsigned short* chunks[5] = {T0, T1, T2, T3, T4};
  int tid = threadIdx.x;
  int wave = tid >> 6, lane = tid & 63;
  int lrow = lane & 15, quad = lane >> 4;
  int rowBase = blockIdx.x * 64;

  f32x4 acc[8];
#pragma unroll
  for (int b = 0; b < 8; ++b) acc[b] = (f32x4){0.f, 0.f, 0.f, 0.f};

  // staging coords
  int ar = tid >> 2, aseg = (tid & 3) * 16;         // A: row 0..63, 16-short seg (2x int4)
  int agrow = min(rowBase + ar, M - 1);             // clamp (garbage rows never stored)
  int bc = tid >> 1, bseg = (tid & 1) * 32;         // B: col 0..127, 32-short seg (4x int4)

  int4 aR0, aR1, bR0, bR1, bR2, bR3;
  {
    const unsigned short* ap = chunks[0] + (size_t)agrow * WID + aseg;
    aR0 = *(const int4*)ap;
    aR1 = *(const int4*)(ap + 8);
    const unsigned short* bp = Wt + (size_t)bc * 640 + bseg;
    bR0 = *(const int4*)bp;
    bR1 = *(const int4*)(bp + 8);
    bR2 = *(const int4*)(bp + 16);
    bR3 = *(const int4*)(bp + 24);
  }

  for (int kc = 0; kc < 10; ++kc) {
    *(int4*)(&As[ar][aseg]) = aR0;
    *(int4*)(&As[ar][aseg + 8]) = aR1;
    *(int4*)(&Bs[bc][bseg]) = bR0;
    *(int4*)(&Bs[bc][bseg + 8]) = bR1;
    *(int4*)(&Bs[bc][bseg + 16]) = bR2;
    *(int4*)(&Bs[bc][bseg + 24]) = bR3;
    __syncthreads();

    if (kc < 9) {  // prefetch next chunk; overlaps the 16 MFMAs below
      int kn = kc + 1;
      const unsigned short* ap =
          chunks[kn >> 1] + (size_t)agrow * WID + (kn & 1) * 64 + aseg;
      aR0 = *(const int4*)ap;
      aR1 = *(const int4*)(ap + 8);
      const unsigned short* bp = Wt + (size_t)bc * 640 + kn * 64 + bseg;
      bR0 = *(const int4*)bp;
      bR1 = *(const int4*)(bp + 8);
      bR2 = *(const int4*)(bp + 16);
      bR3 = *(const int4*)(bp + 24);
    }

    bf16x8 a0 = *(bf16x8*)(&As[wave * 16 + lrow][quad * 8]);
    bf16x8 a1 = *(bf16x8*)(&As[wave * 16 + lrow][32 + quad * 8]);
#pragma unroll
    for (int ct = 0; ct < 8; ++ct) {
      bf16x8 b0 = *(bf16x8*)(&Bs[ct * 16 + lrow][quad * 8]);
      acc[ct] = __builtin_amdgcn_mfma_f32_16x16x32_bf16(a0, b0, acc[ct], 0, 0, 0);
      bf16x8 b1 = *(bf16x8*)(&Bs[ct * 16 + lrow][32 + quad * 8]);
      acc[ct] = __builtin_amdgcn_mfma_f32_16x16x32_bf16(a1, b1, acc[ct], 0, 0, 0);
    }
    __syncthreads();
  }

  // epilogue: C/D layout col=lane&15, row=quad*4+reg ; wave rows rowBase+wave*16+...
  if (mode != 2) {
#pragma unroll
    for (int ct = 0; ct < 8; ++ct) {
      int gcol = ct * 16 + lrow;
      float bv = bias[gcol];
#pragma unroll
      for (int reg = 0; reg < 4; ++reg) {
        int grow = rowBase + wave * 16 + quad * 4 + reg;
        if (grow < M) {
          float v = acc[ct][reg] + bv;
          if (mode == 1) v = fmaxf(v, 0.f);
          Hb[(size_t)grow * WID + gcol] = f2bf(v);
        }
      }
    }
  } else {
    // final layer: y[row] = sum_col (acc+bias)[col] * linw[col] + linb
    float lwv[8], bvv[8];
#pragma unroll
    for (int ct = 0; ct < 8; ++ct) {
      int gcol = ct * 16 + lrow;
      lwv[ct] = linw[gcol];
      bvv[ct] = bias[gcol];
    }
#pragma unroll
    for (int reg = 0; reg < 4; ++reg) {
      float part = 0.f;
#pragma unroll
      for (int ct = 0; ct < 8; ++ct) part += (acc[ct][reg] + bvv[ct]) * lwv[ct];
#pragma unroll
      for (int off = 1; off < 16; off <<= 1) part += __shfl_xor(part, off, 16);
      int grow = rowBase + wave * 16 + quad * 4 + reg;
      if (lrow == 0 && grow < M) y[grow] = part + linb[0];
    }
  }
}

// ---------------- host orchestration ----------------

extern "C" void kernel_launch(void* const* d_in, const int* in_sizes, int n_in,
                              void* d_out, int out_size, void* d_ws, size_t ws_size,
                              hipStream_t stream) {
  const float* x = (const float*)d_in[0];
  const int* ei = (const int*)d_in[1];          // int32 per harness contract
  const float* conv_w = (const float*)d_in[2];  // [6][5][128][128]
  const float* conv_b = (const float*)d_in[3];  // [6][128]
  const float* lin_w = (const float*)d_in[4];   // [128]
  const float* lin_b = (const float*)d_in[5];   // [1]

  const int N = NN, E = NE, C = WID, L = 6;
  const int NB = (N + 255) / 256;

  char* ws = (char*)d_ws;
  size_t off = 0;
  auto alloc = [&](size_t bytes) -> void* {
    void* p = ws + off;
    off = (off + bytes + 255) & ~(size_t)255;
    return p;
  };
  int* deg = (int*)alloc((size_t)N * 4);
  float* dinv = (float*)alloc((size_t)N * 4);
  int* row_start = (int*)alloc((size_t)(N + 1) * 4);
  int* fill_ptr = (int*)alloc((size_t)N * 4);
  int* lex = (int*)alloc((size_t)N * 4);
  int* bsum = (int*)alloc((size_t)NB * 4);
  int* boff = (int*)alloc((size_t)NB * 4);
  unsigned int* csr = (unsigned int*)alloc((size_t)E * 4);
  unsigned short* Xbf = (unsigned short*)alloc((size_t)N * C * 2);
  unsigned short* Hb0 = (unsigned short*)alloc((size_t)N * C * 2);
  unsigned short* Hb1 = (unsigned short*)alloc((size_t)N * C * 2);
  unsigned short* T1b = (unsigned short*)alloc((size_t)N * C * 2);
  unsigned short* T2b = (unsigned short*)alloc((size_t)N * C * 2);
  unsigned short* T3b = (unsigned short*)alloc((size_t)N * C * 2);
  unsigned short* T4b = (unsigned short*)alloc((size_t)N * C * 2);
  unsigned short* Wt = (unsigned short*)alloc((size_t)L * C * 640 * 2);

  // preprocessing
  hipMemsetAsync(deg, 0, (size_t)N * 4, stream);
  degree_kernel<<<(E + 255) / 256, 256, 0, stream>>>(ei, deg, E);
  scan1_kernel<<<NB, 256, 0, stream>>>(deg, lex, bsum, dinv, N);
  scan2_kernel<<<1, 256, 0, stream>>>(bsum, boff, &row_start[N], NB);
  scan3_kernel<<<NB, 256, 0, stream>>>(lex, boff, row_start, fill_ptr, N);
  fill_kernel<<<(E + 255) / 256, 256, 0, stream>>>(ei, dinv, fill_ptr, csr, E);
  {
    int nx = N * C, nw = L * C * 640;
    cvt_kernel<<<(nx + nw + 255) / 256, 256, 0, stream>>>(x, Xbf, conv_w, Wt, nx, nw);
  }

  const int gg = (N + 63) / 64;     // gemm grid (64 rows/block)

  for (int l = 0; l < L; ++l) {
    const unsigned short* T0 = (l == 0) ? Xbf : ((l & 1) ? Hb0 : Hb1);
    unsigned short* Hb = (l & 1) ? Hb1 : Hb0;
    int mode = (l < L - 1) ? 1 : 2;   // 1 = ReLU->Hb, 2 = final fused linear -> y

    prop_kernel<<<PROP_BLOCKS, 256, 0, stream>>>(T1b, T0, nullptr, 1.0f, row_start, csr, N);
    prop_kernel<<<PROP_BLOCKS, 256, 0, stream>>>(T2b, T1b, T0, 2.0f, row_start, csr, N);
    prop_kernel<<<PROP_BLOCKS, 256, 0, stream>>>(T3b, T2b, T1b, 2.0f, row_start, csr, N);
    prop_kernel<<<PROP_BLOCKS, 256, 0, stream>>>(T4b, T3b, T2b, 2.0f, row_start, csr, N);
    cheb_gemm<<<gg, 256, 0, stream>>>(T0, T1b, T2b, T3b, T4b,
                                      Wt + (size_t)l * C * 640, conv_b + (size_t)l * C,
                                      Hb, lin_w, lin_b, (float*)d_out, N, mode);
  }
}